// Round 4
// baseline (690.209 us; speedup 1.0000x reference)
//
#include <hip/hip_runtime.h>
#include <math.h>

#define B 8
#define M 8192
#define N 512
#define R 256
#define EPSF 1e-16f

typedef __attribute__((ext_vector_type(8))) short short8;
typedef __attribute__((ext_vector_type(16))) float f32x16;

__device__ __forceinline__ unsigned short bf16_rtn(float f) {
    unsigned int u = __float_as_uint(f);
    u += 0x7FFFu + ((u >> 16) & 1u);
    return (unsigned short)(u >> 16);
}

// async global->LDS, 16B per lane. LDS dest = wave-uniform base + lane*16.
__device__ __forceinline__ void gll16(const unsigned short* g, unsigned short* l) {
    __builtin_amdgcn_global_load_lds(
        (const __attribute__((address_space(1))) unsigned int*)g,
        (__attribute__((address_space(3))) unsigned int*)l, 16, 0, 0);
}

// ---------------------------------------------------------------------------
// Kc: gather centers x[b, inds, :] -> c_hi/c_lo (split bf16) + exact fp32 v2.
// ---------------------------------------------------------------------------
__global__ __launch_bounds__(256) void ekm_kc(
    const float* __restrict__ x, const int* __restrict__ inds,
    unsigned short* __restrict__ c_hi, unsigned short* __restrict__ c_lo,
    float* __restrict__ v2g)
{
    const int t = threadIdx.x, b = blockIdx.y;
    const int r = blockIdx.x * 16 + (t >> 4);
    const int seg = (t & 15) * 32;
    const float* src = x + ((size_t)b * M + inds[r]) * N + seg;
    unsigned short* hd = c_hi + ((size_t)b * R + r) * 512 + seg;
    unsigned short* ld = c_lo + ((size_t)b * R + r) * 512 + seg;
    float vp = 0.f;
#pragma unroll
    for (int c = 0; c < 4; ++c) {
        float4 f0 = *(const float4*)(src + c * 8);
        float4 f1 = *(const float4*)(src + c * 8 + 4);
        float av[8] = {f0.x, f0.y, f0.z, f0.w, f1.x, f1.y, f1.z, f1.w};
        unsigned ph[4], pl[4];
#pragma unroll
        for (int j = 0; j < 4; ++j) {
            vp += av[2*j] * av[2*j] + av[2*j+1] * av[2*j+1];
            unsigned short h0 = bf16_rtn(av[2*j]), h1 = bf16_rtn(av[2*j+1]);
            float r0 = av[2*j]   - __uint_as_float((unsigned)h0 << 16);
            float r1 = av[2*j+1] - __uint_as_float((unsigned)h1 << 16);
            ph[j] = (unsigned)h0 | ((unsigned)h1 << 16);
            pl[j] = (unsigned)bf16_rtn(r0) | ((unsigned)bf16_rtn(r1) << 16);
        }
        *(uint4*)(hd + c * 8) = make_uint4(ph[0], ph[1], ph[2], ph[3]);
        *(uint4*)(ld + c * 8) = make_uint4(pl[0], pl[1], pl[2], pl[3]);
    }
    vp += __shfl_xor(vp, 1); vp += __shfl_xor(vp, 2);
    vp += __shfl_xor(vp, 4); vp += __shfl_xor(vp, 8);
    if ((t & 15) == 0) v2g[b * R + r] = vp;
}

// ---------------------------------------------------------------------------
// K1: split-bf16 32x32x16 MFMA distances + fused softmax.
// T14 reg-staged pipeline: tile t+1 loaded into REGISTERS a full step early
// (>=1500 cy cover), ds_written from regs after the readers' barrier. Raw
// s_barrier + lgkmcnt(0) only -- NO vmcnt drain anywhere in the loop.
// M-tile 32 rows: acc = 32 AGPR, freeing 32 VGPR for the B stage buffer.
// LDS 36 KB -> 4 blocks/CU; grid (256,8) = two exact 4-resident rounds.
// Numerics bit-identical to R3 (same bytes in same LDS slots, same MFMA order).
// ---------------------------------------------------------------------------
__global__ __launch_bounds__(256, 4) void ekm_k1(
    const float* __restrict__ x, const float* __restrict__ alpha_p,
    const unsigned short* __restrict__ c_hi, const unsigned short* __restrict__ c_lo,
    const float* __restrict__ v2g, float* __restrict__ u_out,
    unsigned short* __restrict__ uT, unsigned short* __restrict__ xT,
    float* __restrict__ colsum)
{
    __shared__ unsigned short Ah[32 * 32], Al[32 * 32];   // 2 KB each, swizzled
    __shared__ unsigned short Bh[256 * 32], Bl[256 * 32]; // 16 KB each, swizzled
    // total LDS = 36864 B -> 4 blocks/CU

    const int t = threadIdx.x;
    const int b = blockIdx.y;
    const int m0 = blockIdx.x * 32;
    const int w = t >> 6, l = t & 63, col = l & 31, h5 = l >> 5;
    const int arow = t >> 3, kc8 = t & 7;        // A staging: 32 rows x 8 k-quads
    const int cswz = (t & 3) ^ ((t >> 3) & 3);   // B source chunk (unchanged)
    const int pswz = (col >> 1) & 3;             // B fragment-read chunk XOR
    const int aswz = (col >> 3) & 3;             // A fragment-read chunk XOR
    const int awi = arow * 32 + ((kc8 >> 1) ^ ((arow >> 3) & 3)) * 8 + (kc8 & 1) * 4;

    const float* ax = x + ((size_t)b * M + m0 + arow) * N + kc8 * 4;
    const unsigned short* bhs = c_hi + ((size_t)b * R + (t >> 2)) * 512 + cswz * 8;
    const unsigned short* bls = c_lo + ((size_t)b * R + (t >> 2)) * 512 + cswz * 8;

    f32x16 acc[2];
    acc[0] = (f32x16)0.f; acc[1] = (f32x16)0.f;

    float x2p = 0.f;
    float4 a0;
    unsigned ph0, ph1, pl0, pl1;
    uint4 rbh[4], rbl[4];                        // B reg-stage (32 VGPR)

    auto loadB = [&](int k0) {
#pragma unroll
        for (int i = 0; i < 4; ++i) {
            rbh[i] = *(const uint4*)(bhs + k0 + i * (64 * 512));
            rbl[i] = *(const uint4*)(bls + k0 + i * (64 * 512));
        }
    };
    auto writeB = [&](void) {
#pragma unroll
        for (int i = 0; i < 4; ++i) {
            *(uint4*)&Bh[i * 2048 + t * 8] = rbh[i];
            *(uint4*)&Bl[i * 2048 + t * 8] = rbl[i];
        }
    };
    auto convertA = [&](void) {                  // a0 -> split bf16, exact x2
        float av[4] = {a0.x, a0.y, a0.z, a0.w};
        x2p += av[0]*av[0] + av[1]*av[1] + av[2]*av[2] + av[3]*av[3];
        unsigned short h0 = bf16_rtn(av[0]), h1 = bf16_rtn(av[1]);
        unsigned short h2 = bf16_rtn(av[2]), h3 = bf16_rtn(av[3]);
        float r0 = av[0] - __uint_as_float((unsigned)h0 << 16);
        float r1 = av[1] - __uint_as_float((unsigned)h1 << 16);
        float r2 = av[2] - __uint_as_float((unsigned)h2 << 16);
        float r3 = av[3] - __uint_as_float((unsigned)h3 << 16);
        ph0 = (unsigned)h0 | ((unsigned)h1 << 16);
        ph1 = (unsigned)h2 | ((unsigned)h3 << 16);
        pl0 = (unsigned)bf16_rtn(r0) | ((unsigned)bf16_rtn(r1) << 16);
        pl1 = (unsigned)bf16_rtn(r2) | ((unsigned)bf16_rtn(r3) << 16);
    };
    auto writeA = [&](void) {
        *(uint2*)&Ah[awi] = make_uint2(ph0, ph1);
        *(uint2*)&Al[awi] = make_uint2(pl0, pl1);
    };
    auto mfma_tile = [&](void) {
#pragma unroll
        for (int half = 0; half < 2; ++half) {
            const int pa = (half * 2 + h5) ^ aswz;
            const int pc = (half * 2 + h5) ^ pswz;
            short8 ah = *(const short8*)&Ah[col * 32 + pa * 8];
            short8 al = *(const short8*)&Al[col * 32 + pa * 8];
            short8 bh[2], bl2[2];
#pragma unroll
            for (int tr = 0; tr < 2; ++tr) {
                bh[tr]  = *(const short8*)&Bh[(w*64 + tr*32 + col) * 32 + pc * 8];
                bl2[tr] = *(const short8*)&Bl[(w*64 + tr*32 + col) * 32 + pc * 8];
            }
#pragma unroll
            for (int tr = 0; tr < 2; ++tr) {
                acc[tr] = __builtin_amdgcn_mfma_f32_32x32x16_bf16(ah, bh[tr],  acc[tr], 0, 0, 0);
                acc[tr] = __builtin_amdgcn_mfma_f32_32x32x16_bf16(ah, bl2[tr], acc[tr], 0, 0, 0);
                acc[tr] = __builtin_amdgcn_mfma_f32_32x32x16_bf16(al, bh[tr],  acc[tr], 0, 0, 0);
            }
        }
    };
    auto xt_store = [&](int k0) {   // xT[k0+kk][m0..m0+31], coalesced 8B stores
        int kk = t >> 3, ms = (t & 7) * 4;
        unsigned short vv[4];
#pragma unroll
        for (int j = 0; j < 4; ++j) {
            int row = ms + j;
            vv[j] = Ah[row * 32 + (((kk >> 3) ^ ((row >> 3) & 3)) << 3) + (kk & 7)];
        }
        *(uint2*)(xT + ((size_t)b * N + k0 + kk) * M + m0 + ms) =
            make_uint2((unsigned)vv[0] | ((unsigned)vv[1] << 16),
                       (unsigned)vv[2] | ((unsigned)vv[3] << 16));
    };

    // ---- prologue: tile 0 -> LDS, tile 1 -> regs ----
    a0 = *(const float4*)(ax);
    loadB(0);
    convertA();
    writeA(); writeB();
    a0 = *(const float4*)(ax + 32);
    loadB(32);
    asm volatile("s_waitcnt lgkmcnt(0)" ::: "memory");
    __builtin_amdgcn_sched_barrier(0);
    __builtin_amdgcn_s_barrier();
    __builtin_amdgcn_sched_barrier(0);

    // ---- main loop: consume tile t (LDS), stage tile t+1 regs->LDS,
    //      issue loads for tile t+2. No vmcnt drain anywhere. ----
    for (int k0 = 0; k0 < N - 32; k0 += 32) {
        xt_store(k0);
        mfma_tile();
        convertA();                              // tile k0+32 (VALU fills barrier wait)
        __builtin_amdgcn_sched_barrier(0);
        __builtin_amdgcn_s_barrier();            // all readers of current tile done
        __builtin_amdgcn_sched_barrier(0);
        writeA(); writeB();                      // tile k0+32 into LDS (from regs)
        if (k0 + 64 < N) {
            a0 = *(const float4*)(ax + k0 + 64); // issue tile k0+64 loads
            loadB(k0 + 64);
        }
        asm volatile("s_waitcnt lgkmcnt(0)" ::: "memory");
        __builtin_amdgcn_sched_barrier(0);
        __builtin_amdgcn_s_barrier();            // new tile visible
        __builtin_amdgcn_sched_barrier(0);
    }
    xt_store(N - 32);
    mfma_tile();

    // ---- epilogue (scratch aliases now-dead LDS) ----
    __syncthreads();                                  // all loop LDS reads done
    float* x2s = (float*)&Ah[0];                      // 128 B
    float (*redm)[32] = (float (*)[32])&Al[0];        // 512 B
    float (*reds)[32] = (float (*)[32])&Bh[0];        // 512 B

    x2p += __shfl_xor(x2p, 1);
    x2p += __shfl_xor(x2p, 2);
    x2p += __shfl_xor(x2p, 4);
    if (kc8 == 0) x2s[arow] = x2p;
    __syncthreads();

    const float ia = 1.4426950408889634f / alpha_p[0];  // log2(e)/alpha
    float v2c[2];
#pragma unroll
    for (int tr = 0; tr < 2; ++tr)
        v2c[tr] = v2g[b * R + w * 64 + tr * 32 + col];

    // d = relu(x2 - 2xv + v2); wave-local row min; stage to LDS
#pragma unroll
    for (int reg = 0; reg < 16; ++reg) {
        int rowl = (reg & 3) + 8 * (reg >> 2) + 4 * h5;
        float x2v = x2s[rowl];
        float mn;
#pragma unroll
        for (int tr = 0; tr < 2; ++tr) {
            float d = x2v - 2.f * acc[tr][reg] + v2c[tr];
            d = fmaxf(d, 0.f);
            acc[tr][reg] = d;
            mn = (tr == 0) ? d : fminf(mn, d);
        }
        mn = fminf(mn, __shfl_xor(mn, 1));
        mn = fminf(mn, __shfl_xor(mn, 2));
        mn = fminf(mn, __shfl_xor(mn, 4));
        mn = fminf(mn, __shfl_xor(mn, 8));
        mn = fminf(mn, __shfl_xor(mn, 16));
        if (col == 0) redm[w][rowl] = mn;
    }
    __syncthreads();

    // exp + row sum
#pragma unroll
    for (int reg = 0; reg < 16; ++reg) {
        int m = (reg & 3) + 8 * (reg >> 2) + 4 * h5;
        float mn = fminf(fminf(redm[0][m], redm[1][m]), fminf(redm[2][m], redm[3][m]));
        float s = 0.f;
#pragma unroll
        for (int tr = 0; tr < 2; ++tr) {
            float e = exp2f((mn - acc[tr][reg]) * ia);
            acc[tr][reg] = e;
            s += e;
        }
        s += __shfl_xor(s, 1); s += __shfl_xor(s, 2); s += __shfl_xor(s, 4);
        s += __shfl_xor(s, 8); s += __shfl_xor(s, 16);
        if (col == 0) reds[w][m] = s;
    }
    __syncthreads();

    // normalize, write u (fp32), accumulate colsum, pack uT (bf16)
    float* ub = u_out + ((size_t)b * M + m0) * R + w * 64;
    float cs[2] = {0.f, 0.f};
#pragma unroll
    for (int reg = 0; reg < 16; ++reg) {
        int m = (reg & 3) + 8 * (reg >> 2) + 4 * h5;
        float inv = 1.f / (reds[0][m] + reds[1][m] + reds[2][m] + reds[3][m]);
#pragma unroll
        for (int tr = 0; tr < 2; ++tr) {
            float uu = acc[tr][reg] * inv;
            acc[tr][reg] = uu;
            ub[(size_t)m * R + tr * 32 + col] = uu;
            cs[tr] += uu;
        }
    }
    unsigned short* uTb = uT + ((size_t)b * R + w * 64) * M + m0;
#pragma unroll
    for (int tr = 0; tr < 2; ++tr)
#pragma unroll
    for (int rq = 0; rq < 4; ++rq) {
        uint2 p;
        p.x = (unsigned)bf16_rtn(acc[tr][rq*4+0]) | ((unsigned)bf16_rtn(acc[tr][rq*4+1]) << 16);
        p.y = (unsigned)bf16_rtn(acc[tr][rq*4+2]) | ((unsigned)bf16_rtn(acc[tr][rq*4+3]) << 16);
        *(uint2*)(uTb + (size_t)(tr*32 + col) * M + 8*rq + 4*h5) = p;
    }
    cs[0] += __shfl_xor(cs[0], 32);
    cs[1] += __shfl_xor(cs[1], 32);
    if (h5 == 0) {
        atomicAdd(&colsum[b * R + w * 64 + col], cs[0]);
        atomicAdd(&colsum[b * R + w * 64 + 32 + col], cs[1]);
    }
}

// ---------------------------------------------------------------------------
// K2: part[slab][b][n][r] = sum_{m in slab} xT[n][m]*uT[r][m].
// R0 version (proven; restructuring measured neutral in R1/R2).
// ---------------------------------------------------------------------------
__global__ __launch_bounds__(256, 2) void ekm_k2(
    const unsigned short* __restrict__ xT, const unsigned short* __restrict__ uT,
    float* __restrict__ part)
{
    __shared__ unsigned short XA[128 * 32], UB[128 * 32];
    const int t = threadIdx.x;
    const int nt = blockIdx.x >> 1, rt = blockIdx.x & 1;
    const int slab = blockIdx.y, b = blockIdx.z;
    const int n0 = nt * 128, r0 = rt * 128;
    const int w = t >> 6, l = t & 63, col = l & 31, h5 = l >> 5;
    const int wn = w >> 1, wr = w & 1;
    const int cswz = (t & 3) ^ ((t >> 3) & 3);
    const int pswz = (col >> 1) & 3;

    const unsigned short* xs = xT + ((size_t)b * N + n0 + (t >> 2)) * M + slab * 1024 + cswz * 8;
    const unsigned short* us = uT + ((size_t)b * R + r0 + (t >> 2)) * M + slab * 1024 + cswz * 8;

    f32x16 acc[2][2];
    acc[0][0] = (f32x16)0.f; acc[0][1] = (f32x16)0.f;
    acc[1][0] = (f32x16)0.f; acc[1][1] = (f32x16)0.f;

    for (int k0 = 0; k0 < 1024; k0 += 32) {
        __syncthreads();
#pragma unroll
        for (int i = 0; i < 2; ++i) {
            gll16(xs + k0 + (size_t)i * 64 * M, XA + i * 2048 + t * 8);
            gll16(us + k0 + (size_t)i * 64 * M, UB + i * 2048 + t * 8);
        }
        __syncthreads();
#pragma unroll
        for (int half = 0; half < 2; ++half) {
            const int pc = (half * 2 + h5) ^ pswz;
            short8 af[2], bf2[2];
#pragma unroll
            for (int tm = 0; tm < 2; ++tm)
                af[tm] = *(const short8*)&XA[(wn*64 + tm*32 + col) * 32 + pc*8];
#pragma unroll
            for (int tr = 0; tr < 2; ++tr)
                bf2[tr] = *(const short8*)&UB[(wr*64 + tr*32 + col) * 32 + pc*8];
#pragma unroll
            for (int tm = 0; tm < 2; ++tm)
#pragma unroll
            for (int tr = 0; tr < 2; ++tr)
                acc[tm][tr] = __builtin_amdgcn_mfma_f32_32x32x16_bf16(af[tm], bf2[tr], acc[tm][tr], 0, 0, 0);
        }
    }

    float* pb = part + (size_t)slab * ((size_t)B * N * R) + (size_t)b * N * R;
#pragma unroll
    for (int tm = 0; tm < 2; ++tm)
#pragma unroll
    for (int reg = 0; reg < 16; ++reg) {
        int n = n0 + wn*64 + tm*32 + (reg & 3) + 8*(reg >> 2) + 4*h5;
#pragma unroll
        for (int tr = 0; tr < 2; ++tr)
            pb[(size_t)n * R + r0 + wr*64 + tr*32 + col] = acc[tm][tr][reg];
    }
}

// ---------------------------------------------------------------------------
// Kred: v = (sum of 8 partial slabs) / (colsum + eps), float4 per thread.
// ---------------------------------------------------------------------------
__global__ __launch_bounds__(256) void ekm_red(
    const float* __restrict__ part, const float* __restrict__ colsum,
    float* __restrict__ v_out)
{
    size_t o = ((size_t)blockIdx.x * 256 + threadIdx.x) * 4;
    float sx = 0.f, sy = 0.f, sz = 0.f, sw = 0.f;
#pragma unroll
    for (int sl = 0; sl < 8; ++sl) {
        float4 p = *(const float4*)(part + (size_t)sl * B * N * R + o);
        sx += p.x; sy += p.y; sz += p.z; sw += p.w;
    }
    int b = (int)(o >> 17);           // N*R = 131072
    int r = (int)(o & (R - 1));
    float4 cs = *(const float4*)(colsum + b * R + r);
    float4 vo;
    vo.x = sx / (cs.x + EPSF);
    vo.y = sy / (cs.y + EPSF);
    vo.z = sz / (cs.z + EPSF);
    vo.w = sw / (cs.w + EPSF);
    *(float4*)(v_out + o) = vo;
}

extern "C" void kernel_launch(void* const* d_in, const int* in_sizes, int n_in,
                              void* d_out, int out_size, void* d_ws, size_t ws_size,
                              hipStream_t stream) {
    const float* x     = (const float*)d_in[0];
    const float* alpha = (const float*)d_in[1];
    const int*   inds  = (const int*)d_in[2];

    float* u_out = (float*)d_out;                    // B*M*R fp32
    float* v_out = u_out + (size_t)B * M * R;        // B*N*R fp32

    char* ws = (char*)d_ws;
    const size_t CH = (size_t)B * R * 512 * 2;       // 2 MB   c_hi / c_lo
    unsigned short* c_hi   = (unsigned short*)ws;
    unsigned short* c_lo   = (unsigned short*)(ws + CH);
    float*          v2g    = (float*)(ws + 2 * CH);
    float*          colsum = (float*)(ws + 2 * CH + (size_t)B * R * 4);
    char* p = ws + 2 * CH + 2 * (size_t)B * R * 4;
    unsigned short* xT = (unsigned short*)p;          p += (size_t)B * N * M * 2;  // 67 MB
    unsigned short* uT = (unsigned short*)p;          p += (size_t)B * R * M * 2;  // 33.5 MB
    float*          part = (float*)p;                 // 8 * B*N*R * 4 = 33.5 MB

    hipMemsetAsync(colsum, 0, (size_t)B * R * sizeof(float), stream);

    ekm_kc<<<dim3(16, B), 256, 0, stream>>>(x, inds, c_hi, c_lo, v2g);
    ekm_k1<<<dim3(M / 32, B), 256, 0, stream>>>(x, alpha, c_hi, c_lo, v2g,
                                                u_out, uT, xT, colsum);
    ekm_k2<<<dim3(8, 8, B), 256, 0, stream>>>(xT, uT, part);
    ekm_red<<<(B * N * R / 4) / 256, 256, 0, stream>>>(part, colsum, v_out);
}

// Round 5
// 682.946 us; speedup vs baseline: 1.0106x; 1.0106x over previous
//
#include <hip/hip_runtime.h>
#include <math.h>

#define B 8
#define M 8192
#define N 512
#define R 256
#define EPSF 1e-16f

typedef __attribute__((ext_vector_type(8))) short short8;
typedef __attribute__((ext_vector_type(16))) float f32x16;

__device__ __forceinline__ unsigned short bf16_rtn(float f) {
    unsigned int u = __float_as_uint(f);
    u += 0x7FFFu + ((u >> 16) & 1u);
    return (unsigned short)(u >> 16);
}

// async global->LDS, 16B per lane. LDS dest = wave-uniform base + lane*16.
__device__ __forceinline__ void gll16(const unsigned short* g, unsigned short* l) {
    __builtin_amdgcn_global_load_lds(
        (const __attribute__((address_space(1))) unsigned int*)g,
        (__attribute__((address_space(3))) unsigned int*)l, 16, 0, 0);
}

// ---------------------------------------------------------------------------
// Kc: gather centers x[b, inds, :] -> c_hi/c_lo (split bf16) + exact fp32 v2.
// ---------------------------------------------------------------------------
__global__ __launch_bounds__(256) void ekm_kc(
    const float* __restrict__ x, const int* __restrict__ inds,
    unsigned short* __restrict__ c_hi, unsigned short* __restrict__ c_lo,
    float* __restrict__ v2g)
{
    const int t = threadIdx.x, b = blockIdx.y;
    const int r = blockIdx.x * 16 + (t >> 4);
    const int seg = (t & 15) * 32;
    const float* src = x + ((size_t)b * M + inds[r]) * N + seg;
    unsigned short* hd = c_hi + ((size_t)b * R + r) * 512 + seg;
    unsigned short* ld = c_lo + ((size_t)b * R + r) * 512 + seg;
    float vp = 0.f;
#pragma unroll
    for (int c = 0; c < 4; ++c) {
        float4 f0 = *(const float4*)(src + c * 8);
        float4 f1 = *(const float4*)(src + c * 8 + 4);
        float av[8] = {f0.x, f0.y, f0.z, f0.w, f1.x, f1.y, f1.z, f1.w};
        unsigned ph[4], pl[4];
#pragma unroll
        for (int j = 0; j < 4; ++j) {
            vp += av[2*j] * av[2*j] + av[2*j+1] * av[2*j+1];
            unsigned short h0 = bf16_rtn(av[2*j]), h1 = bf16_rtn(av[2*j+1]);
            float r0 = av[2*j]   - __uint_as_float((unsigned)h0 << 16);
            float r1 = av[2*j+1] - __uint_as_float((unsigned)h1 << 16);
            ph[j] = (unsigned)h0 | ((unsigned)h1 << 16);
            pl[j] = (unsigned)bf16_rtn(r0) | ((unsigned)bf16_rtn(r1) << 16);
        }
        *(uint4*)(hd + c * 8) = make_uint4(ph[0], ph[1], ph[2], ph[3]);
        *(uint4*)(ld + c * 8) = make_uint4(pl[0], pl[1], pl[2], pl[3]);
    }
    vp += __shfl_xor(vp, 1); vp += __shfl_xor(vp, 2);
    vp += __shfl_xor(vp, 4); vp += __shfl_xor(vp, 8);
    if ((t & 15) == 0) v2g[b * R + r] = vp;
}

// ---------------------------------------------------------------------------
// K1: split-bf16 32x32x16 MFMA distances + fused softmax.
// T14 reg-staged pipeline (R4 structure), spill-fixed: __launch_bounds__(256,3)
// gives a 170-reg unified budget (R4's (256,4) clamped VGPRs to 64 -> scratch
// spill -> 916 MB write-back). No vmcnt drain anywhere in the K-loop; the
// buffer-load -> ds_write distance is a full K-step (~1500 cy of cover).
// M-tile 32, LDS 36 KB, 3 blocks/CU, grid 2048 = 2.67 resident rounds.
// ---------------------------------------------------------------------------
__global__ __launch_bounds__(256, 3) void ekm_k1(
    const float* __restrict__ x, const float* __restrict__ alpha_p,
    const unsigned short* __restrict__ c_hi, const unsigned short* __restrict__ c_lo,
    const float* __restrict__ v2g, float* __restrict__ u_out,
    unsigned short* __restrict__ uT, unsigned short* __restrict__ xT,
    float* __restrict__ colsum)
{
    __shared__ unsigned short Ah[32 * 32], Al[32 * 32];   // 2 KB each, swizzled
    __shared__ unsigned short Bh[256 * 32], Bl[256 * 32]; // 16 KB each, swizzled
    // total LDS = 36864 B

    const int t = threadIdx.x;
    const int b = blockIdx.y;
    const int m0 = blockIdx.x * 32;
    const int w = t >> 6, l = t & 63, col = l & 31, h5 = l >> 5;
    const int arow = t >> 3, kc8 = t & 7;        // A staging: 32 rows x 8 k-quads
    const int cswz = (t & 3) ^ ((t >> 3) & 3);   // B source chunk (unchanged)
    const int pswz = (col >> 1) & 3;             // B fragment-read chunk XOR
    const int aswz = (col >> 3) & 3;             // A fragment-read chunk XOR
    const int awi = arow * 32 + ((kc8 >> 1) ^ ((arow >> 3) & 3)) * 8 + (kc8 & 1) * 4;

    const float* ax = x + ((size_t)b * M + m0 + arow) * N + kc8 * 4;
    const unsigned short* bhs = c_hi + ((size_t)b * R + (t >> 2)) * 512 + cswz * 8;
    const unsigned short* bls = c_lo + ((size_t)b * R + (t >> 2)) * 512 + cswz * 8;

    f32x16 acc[2];
    acc[0] = (f32x16)0.f; acc[1] = (f32x16)0.f;

    float x2p = 0.f;
    float4 a0;
    unsigned ph0, ph1, pl0, pl1;
    uint4 rbh[4], rbl[4];                        // B reg-stage (32 VGPR)

    auto loadB = [&](int k0) {
#pragma unroll
        for (int i = 0; i < 4; ++i) {
            rbh[i] = *(const uint4*)(bhs + k0 + i * (64 * 512));
            rbl[i] = *(const uint4*)(bls + k0 + i * (64 * 512));
        }
    };
    auto writeB = [&](void) {
#pragma unroll
        for (int i = 0; i < 4; ++i) {
            *(uint4*)&Bh[i * 2048 + t * 8] = rbh[i];
            *(uint4*)&Bl[i * 2048 + t * 8] = rbl[i];
        }
    };
    auto convertA = [&](void) {                  // a0 -> split bf16, exact x2
        float av[4] = {a0.x, a0.y, a0.z, a0.w};
        x2p += av[0]*av[0] + av[1]*av[1] + av[2]*av[2] + av[3]*av[3];
        unsigned short h0 = bf16_rtn(av[0]), h1 = bf16_rtn(av[1]);
        unsigned short h2 = bf16_rtn(av[2]), h3 = bf16_rtn(av[3]);
        float r0 = av[0] - __uint_as_float((unsigned)h0 << 16);
        float r1 = av[1] - __uint_as_float((unsigned)h1 << 16);
        float r2 = av[2] - __uint_as_float((unsigned)h2 << 16);
        float r3 = av[3] - __uint_as_float((unsigned)h3 << 16);
        ph0 = (unsigned)h0 | ((unsigned)h1 << 16);
        ph1 = (unsigned)h2 | ((unsigned)h3 << 16);
        pl0 = (unsigned)bf16_rtn(r0) | ((unsigned)bf16_rtn(r1) << 16);
        pl1 = (unsigned)bf16_rtn(r2) | ((unsigned)bf16_rtn(r3) << 16);
    };
    auto writeA = [&](void) {
        *(uint2*)&Ah[awi] = make_uint2(ph0, ph1);
        *(uint2*)&Al[awi] = make_uint2(pl0, pl1);
    };
    auto mfma_tile = [&](void) {
#pragma unroll
        for (int half = 0; half < 2; ++half) {
            const int pa = (half * 2 + h5) ^ aswz;
            const int pc = (half * 2 + h5) ^ pswz;
            short8 ah = *(const short8*)&Ah[col * 32 + pa * 8];
            short8 al = *(const short8*)&Al[col * 32 + pa * 8];
            short8 bh[2], bl2[2];
#pragma unroll
            for (int tr = 0; tr < 2; ++tr) {
                bh[tr]  = *(const short8*)&Bh[(w*64 + tr*32 + col) * 32 + pc * 8];
                bl2[tr] = *(const short8*)&Bl[(w*64 + tr*32 + col) * 32 + pc * 8];
            }
#pragma unroll
            for (int tr = 0; tr < 2; ++tr) {
                acc[tr] = __builtin_amdgcn_mfma_f32_32x32x16_bf16(ah, bh[tr],  acc[tr], 0, 0, 0);
                acc[tr] = __builtin_amdgcn_mfma_f32_32x32x16_bf16(ah, bl2[tr], acc[tr], 0, 0, 0);
                acc[tr] = __builtin_amdgcn_mfma_f32_32x32x16_bf16(al, bh[tr],  acc[tr], 0, 0, 0);
            }
        }
    };
    auto xt_store = [&](int k0) {   // xT[k0+kk][m0..m0+31], coalesced 8B stores
        int kk = t >> 3, ms = (t & 7) * 4;
        unsigned short vv[4];
#pragma unroll
        for (int j = 0; j < 4; ++j) {
            int row = ms + j;
            vv[j] = Ah[row * 32 + (((kk >> 3) ^ ((row >> 3) & 3)) << 3) + (kk & 7)];
        }
        *(uint2*)(xT + ((size_t)b * N + k0 + kk) * M + m0 + ms) =
            make_uint2((unsigned)vv[0] | ((unsigned)vv[1] << 16),
                       (unsigned)vv[2] | ((unsigned)vv[3] << 16));
    };

    // ---- prologue: tile 0 -> LDS, tile 1 -> regs ----
    a0 = *(const float4*)(ax);
    loadB(0);
    convertA();
    writeA(); writeB();
    a0 = *(const float4*)(ax + 32);
    loadB(32);
    asm volatile("s_waitcnt lgkmcnt(0)" ::: "memory");
    __builtin_amdgcn_sched_barrier(0);
    __builtin_amdgcn_s_barrier();
    __builtin_amdgcn_sched_barrier(0);

    // ---- main loop: consume tile t (LDS), stage tile t+1 regs->LDS,
    //      issue loads for tile t+2. No vmcnt drain anywhere. ----
    for (int k0 = 0; k0 < N - 32; k0 += 32) {
        xt_store(k0);
        mfma_tile();
        convertA();                              // tile k0+32 (VALU fills barrier wait)
        __builtin_amdgcn_sched_barrier(0);
        __builtin_amdgcn_s_barrier();            // all readers of current tile done
        __builtin_amdgcn_sched_barrier(0);
        writeA(); writeB();                      // tile k0+32 into LDS (from regs)
        if (k0 + 64 < N) {
            a0 = *(const float4*)(ax + k0 + 64); // issue tile k0+64 loads
            loadB(k0 + 64);
        }
        asm volatile("s_waitcnt lgkmcnt(0)" ::: "memory");
        __builtin_amdgcn_sched_barrier(0);
        __builtin_amdgcn_s_barrier();            // new tile visible
        __builtin_amdgcn_sched_barrier(0);
    }
    xt_store(N - 32);
    mfma_tile();

    // ---- epilogue (scratch aliases now-dead LDS) ----
    __syncthreads();                                  // all loop LDS reads done
    float* x2s = (float*)&Ah[0];                      // 128 B
    float (*redm)[32] = (float (*)[32])&Al[0];        // 512 B
    float (*reds)[32] = (float (*)[32])&Bh[0];        // 512 B

    x2p += __shfl_xor(x2p, 1);
    x2p += __shfl_xor(x2p, 2);
    x2p += __shfl_xor(x2p, 4);
    if (kc8 == 0) x2s[arow] = x2p;
    __syncthreads();

    const float ia = 1.4426950408889634f / alpha_p[0];  // log2(e)/alpha
    float v2c[2];
#pragma unroll
    for (int tr = 0; tr < 2; ++tr)
        v2c[tr] = v2g[b * R + w * 64 + tr * 32 + col];

    // d = relu(x2 - 2xv + v2); wave-local row min; stage to LDS
#pragma unroll
    for (int reg = 0; reg < 16; ++reg) {
        int rowl = (reg & 3) + 8 * (reg >> 2) + 4 * h5;
        float x2v = x2s[rowl];
        float mn;
#pragma unroll
        for (int tr = 0; tr < 2; ++tr) {
            float d = x2v - 2.f * acc[tr][reg] + v2c[tr];
            d = fmaxf(d, 0.f);
            acc[tr][reg] = d;
            mn = (tr == 0) ? d : fminf(mn, d);
        }
        mn = fminf(mn, __shfl_xor(mn, 1));
        mn = fminf(mn, __shfl_xor(mn, 2));
        mn = fminf(mn, __shfl_xor(mn, 4));
        mn = fminf(mn, __shfl_xor(mn, 8));
        mn = fminf(mn, __shfl_xor(mn, 16));
        if (col == 0) redm[w][rowl] = mn;
    }
    __syncthreads();

    // exp + row sum
#pragma unroll
    for (int reg = 0; reg < 16; ++reg) {
        int m = (reg & 3) + 8 * (reg >> 2) + 4 * h5;
        float mn = fminf(fminf(redm[0][m], redm[1][m]), fminf(redm[2][m], redm[3][m]));
        float s = 0.f;
#pragma unroll
        for (int tr = 0; tr < 2; ++tr) {
            float e = exp2f((mn - acc[tr][reg]) * ia);
            acc[tr][reg] = e;
            s += e;
        }
        s += __shfl_xor(s, 1); s += __shfl_xor(s, 2); s += __shfl_xor(s, 4);
        s += __shfl_xor(s, 8); s += __shfl_xor(s, 16);
        if (col == 0) reds[w][m] = s;
    }
    __syncthreads();

    // normalize, write u (fp32), accumulate colsum, pack uT (bf16)
    float* ub = u_out + ((size_t)b * M + m0) * R + w * 64;
    float cs[2] = {0.f, 0.f};
#pragma unroll
    for (int reg = 0; reg < 16; ++reg) {
        int m = (reg & 3) + 8 * (reg >> 2) + 4 * h5;
        float inv = 1.f / (reds[0][m] + reds[1][m] + reds[2][m] + reds[3][m]);
#pragma unroll
        for (int tr = 0; tr < 2; ++tr) {
            float uu = acc[tr][reg] * inv;
            acc[tr][reg] = uu;
            ub[(size_t)m * R + tr * 32 + col] = uu;
            cs[tr] += uu;
        }
    }
    unsigned short* uTb = uT + ((size_t)b * R + w * 64) * M + m0;
#pragma unroll
    for (int tr = 0; tr < 2; ++tr)
#pragma unroll
    for (int rq = 0; rq < 4; ++rq) {
        uint2 p;
        p.x = (unsigned)bf16_rtn(acc[tr][rq*4+0]) | ((unsigned)bf16_rtn(acc[tr][rq*4+1]) << 16);
        p.y = (unsigned)bf16_rtn(acc[tr][rq*4+2]) | ((unsigned)bf16_rtn(acc[tr][rq*4+3]) << 16);
        *(uint2*)(uTb + (size_t)(tr*32 + col) * M + 8*rq + 4*h5) = p;
    }
    cs[0] += __shfl_xor(cs[0], 32);
    cs[1] += __shfl_xor(cs[1], 32);
    if (h5 == 0) {
        atomicAdd(&colsum[b * R + w * 64 + col], cs[0]);
        atomicAdd(&colsum[b * R + w * 64 + 32 + col], cs[1]);
    }
}

// ---------------------------------------------------------------------------
// K2: part[slab][b][n][r] = sum_{m in slab} xT[n][m]*uT[r][m].
// R0 version (proven; restructuring measured neutral in R1/R2).
// ---------------------------------------------------------------------------
__global__ __launch_bounds__(256, 2) void ekm_k2(
    const unsigned short* __restrict__ xT, const unsigned short* __restrict__ uT,
    float* __restrict__ part)
{
    __shared__ unsigned short XA[128 * 32], UB[128 * 32];
    const int t = threadIdx.x;
    const int nt = blockIdx.x >> 1, rt = blockIdx.x & 1;
    const int slab = blockIdx.y, b = blockIdx.z;
    const int n0 = nt * 128, r0 = rt * 128;
    const int w = t >> 6, l = t & 63, col = l & 31, h5 = l >> 5;
    const int wn = w >> 1, wr = w & 1;
    const int cswz = (t & 3) ^ ((t >> 3) & 3);
    const int pswz = (col >> 1) & 3;

    const unsigned short* xs = xT + ((size_t)b * N + n0 + (t >> 2)) * M + slab * 1024 + cswz * 8;
    const unsigned short* us = uT + ((size_t)b * R + r0 + (t >> 2)) * M + slab * 1024 + cswz * 8;

    f32x16 acc[2][2];
    acc[0][0] = (f32x16)0.f; acc[0][1] = (f32x16)0.f;
    acc[1][0] = (f32x16)0.f; acc[1][1] = (f32x16)0.f;

    for (int k0 = 0; k0 < 1024; k0 += 32) {
        __syncthreads();
#pragma unroll
        for (int i = 0; i < 2; ++i) {
            gll16(xs + k0 + (size_t)i * 64 * M, XA + i * 2048 + t * 8);
            gll16(us + k0 + (size_t)i * 64 * M, UB + i * 2048 + t * 8);
        }
        __syncthreads();
#pragma unroll
        for (int half = 0; half < 2; ++half) {
            const int pc = (half * 2 + h5) ^ pswz;
            short8 af[2], bf2[2];
#pragma unroll
            for (int tm = 0; tm < 2; ++tm)
                af[tm] = *(const short8*)&XA[(wn*64 + tm*32 + col) * 32 + pc*8];
#pragma unroll
            for (int tr = 0; tr < 2; ++tr)
                bf2[tr] = *(const short8*)&UB[(wr*64 + tr*32 + col) * 32 + pc*8];
#pragma unroll
            for (int tm = 0; tm < 2; ++tm)
#pragma unroll
            for (int tr = 0; tr < 2; ++tr)
                acc[tm][tr] = __builtin_amdgcn_mfma_f32_32x32x16_bf16(af[tm], bf2[tr], acc[tm][tr], 0, 0, 0);
        }
    }

    float* pb = part + (size_t)slab * ((size_t)B * N * R) + (size_t)b * N * R;
#pragma unroll
    for (int tm = 0; tm < 2; ++tm)
#pragma unroll
    for (int reg = 0; reg < 16; ++reg) {
        int n = n0 + wn*64 + tm*32 + (reg & 3) + 8*(reg >> 2) + 4*h5;
#pragma unroll
        for (int tr = 0; tr < 2; ++tr)
            pb[(size_t)n * R + r0 + wr*64 + tr*32 + col] = acc[tm][tr][reg];
    }
}

// ---------------------------------------------------------------------------
// Kred: v = (sum of 8 partial slabs) / (colsum + eps), float4 per thread.
// ---------------------------------------------------------------------------
__global__ __launch_bounds__(256) void ekm_red(
    const float* __restrict__ part, const float* __restrict__ colsum,
    float* __restrict__ v_out)
{
    size_t o = ((size_t)blockIdx.x * 256 + threadIdx.x) * 4;
    float sx = 0.f, sy = 0.f, sz = 0.f, sw = 0.f;
#pragma unroll
    for (int sl = 0; sl < 8; ++sl) {
        float4 p = *(const float4*)(part + (size_t)sl * B * N * R + o);
        sx += p.x; sy += p.y; sz += p.z; sw += p.w;
    }
    int b = (int)(o >> 17);           // N*R = 131072
    int r = (int)(o & (R - 1));
    float4 cs = *(const float4*)(colsum + b * R + r);
    float4 vo;
    vo.x = sx / (cs.x + EPSF);
    vo.y = sy / (cs.y + EPSF);
    vo.z = sz / (cs.z + EPSF);
    vo.w = sw / (cs.w + EPSF);
    *(float4*)(v_out + o) = vo;
}

extern "C" void kernel_launch(void* const* d_in, const int* in_sizes, int n_in,
                              void* d_out, int out_size, void* d_ws, size_t ws_size,
                              hipStream_t stream) {
    const float* x     = (const float*)d_in[0];
    const float* alpha = (const float*)d_in[1];
    const int*   inds  = (const int*)d_in[2];

    float* u_out = (float*)d_out;                    // B*M*R fp32
    float* v_out = u_out + (size_t)B * M * R;        // B*N*R fp32

    char* ws = (char*)d_ws;
    const size_t CH = (size_t)B * R * 512 * 2;       // 2 MB   c_hi / c_lo
    unsigned short* c_hi   = (unsigned short*)ws;
    unsigned short* c_lo   = (unsigned short*)(ws + CH);
    float*          v2g    = (float*)(ws + 2 * CH);
    float*          colsum = (float*)(ws + 2 * CH + (size_t)B * R * 4);
    char* p = ws + 2 * CH + 2 * (size_t)B * R * 4;
    unsigned short* xT = (unsigned short*)p;          p += (size_t)B * N * M * 2;  // 67 MB
    unsigned short* uT = (unsigned short*)p;          p += (size_t)B * R * M * 2;  // 33.5 MB
    float*          part = (float*)p;                 // 8 * B*N*R * 4 = 33.5 MB

    hipMemsetAsync(colsum, 0, (size_t)B * R * sizeof(float), stream);

    ekm_kc<<<dim3(16, B), 256, 0, stream>>>(x, inds, c_hi, c_lo, v2g);
    ekm_k1<<<dim3(M / 32, B), 256, 0, stream>>>(x, alpha, c_hi, c_lo, v2g,
                                                u_out, uT, xT, colsum);
    ekm_k2<<<dim3(8, 8, B), 256, 0, stream>>>(xT, uT, part);
    ekm_red<<<(B * N * R / 4) / 256, 256, 0, stream>>>(part, colsum, v_out);
}

// Round 6
// 409.749 us; speedup vs baseline: 1.6845x; 1.6667x over previous
//
#include <hip/hip_runtime.h>
#include <math.h>

#define B 8
#define M 8192
#define N 512
#define R 256
#define EPSF 1e-16f

typedef __attribute__((ext_vector_type(8))) short short8;
typedef __attribute__((ext_vector_type(16))) float f32x16;

__device__ __forceinline__ unsigned short bf16_rtn(float f) {
    unsigned int u = __float_as_uint(f);
    u += 0x7FFFu + ((u >> 16) & 1u);
    return (unsigned short)(u >> 16);
}

// async global->LDS, 16B per lane. LDS dest = wave-uniform base + lane*16.
__device__ __forceinline__ void gll16(const unsigned short* g, unsigned short* l) {
    __builtin_amdgcn_global_load_lds(
        (const __attribute__((address_space(1))) unsigned int*)g,
        (__attribute__((address_space(3))) unsigned int*)l, 16, 0, 0);
}

// ---------------------------------------------------------------------------
// Kc: gather centers x[b, inds, :] -> FRAGMENT-MAJOR split-bf16 panels
//   cpH/cpL[b][kc][rg][lane][8],  kc = k/16 (32), rg = r/32 (8),
//   lane = (k8<<5)|(r&31), element = c[b][r][kc*16 + k8*8 + j].
// In k1 a wave reads one fragment as 64 lanes x 16B contiguous = 1 KB.
// Also exact fp32 v2 row sums.
// ---------------------------------------------------------------------------
__global__ __launch_bounds__(256) void ekm_kc(
    const float* __restrict__ x, const int* __restrict__ inds,
    unsigned short* __restrict__ cpH, unsigned short* __restrict__ cpL,
    float* __restrict__ v2g)
{
    const int t = threadIdx.x, b = blockIdx.y;
    const int r = blockIdx.x * 16 + (t >> 4);
    const int seg = (t & 15) * 32;            // k base (multiple of 32)
    const int rg = r >> 5, rl = r & 31;
    const float* src = x + ((size_t)b * M + inds[r]) * N + seg;
    // panel base for (b, kc = seg>>4, rg); kc stride = 4096 shorts, rg = 512
    unsigned short* hb = cpH + (((size_t)b * 32 + (seg >> 4)) * 8 + rg) * 512;
    unsigned short* lb = cpL + (((size_t)b * 32 + (seg >> 4)) * 8 + rg) * 512;
    float vp = 0.f;
#pragma unroll
    for (int c = 0; c < 4; ++c) {             // 8 k per c; k8 = c&1, kc += c>>1
        float4 f0 = *(const float4*)(src + c * 8);
        float4 f1 = *(const float4*)(src + c * 8 + 4);
        float av[8] = {f0.x, f0.y, f0.z, f0.w, f1.x, f1.y, f1.z, f1.w};
        unsigned ph[4], pl[4];
#pragma unroll
        for (int j = 0; j < 4; ++j) {
            vp += av[2*j] * av[2*j] + av[2*j+1] * av[2*j+1];
            unsigned short h0 = bf16_rtn(av[2*j]), h1 = bf16_rtn(av[2*j+1]);
            float r0 = av[2*j]   - __uint_as_float((unsigned)h0 << 16);
            float r1 = av[2*j+1] - __uint_as_float((unsigned)h1 << 16);
            ph[j] = (unsigned)h0 | ((unsigned)h1 << 16);
            pl[j] = (unsigned)bf16_rtn(r0) | ((unsigned)bf16_rtn(r1) << 16);
        }
        const size_t off = (size_t)(c >> 1) * 4096 + (size_t)((c & 1) * 32 + rl) * 8;
        *(uint4*)(hb + off) = make_uint4(ph[0], ph[1], ph[2], ph[3]);
        *(uint4*)(lb + off) = make_uint4(pl[0], pl[1], pl[2], pl[3]);
    }
    vp += __shfl_xor(vp, 1); vp += __shfl_xor(vp, 2);
    vp += __shfl_xor(vp, 4); vp += __shfl_xor(vp, 8);
    if ((t & 15) == 0) v2g[b * R + r] = vp;
}

// ---------------------------------------------------------------------------
// K1: split-bf16 32x32x16 MFMA distances + fused softmax.
// B operand: DIRECT coalesced fragment loads from L2 panels (no LDS, no gll,
// no vmcnt drain). Loads for step t+1 issued after consuming set t -> a full
// MFMA phase of latency cover, auto vmcnt. B-frags feed MFMA directly (AGPR-
// legal operands -> no ds_write VGPR-partition trap, the R4/R5 failure mode).
// A operand: R3-proven tiny LDS stage (8 KB), lgkmcnt-only barriers.
// b = bid&7 pins each b's 4 MB panel set to one XCD's L2.
// Numerics bit-identical to R3 (same fragment bytes, same MFMA order).
// ---------------------------------------------------------------------------
__global__ __launch_bounds__(256, 3) void ekm_k1(
    const float* __restrict__ x, const float* __restrict__ alpha_p,
    const unsigned short* __restrict__ cpH, const unsigned short* __restrict__ cpL,
    const float* __restrict__ v2g, float* __restrict__ u_out,
    unsigned short* __restrict__ uT, unsigned short* __restrict__ xT,
    float* __restrict__ colsum)
{
    __shared__ unsigned short Ah[64 * 32], Al[64 * 32];   // 8 KB total

    const int t = threadIdx.x;
    const int bid = blockIdx.x;
    const int b = bid & 7;
    const int m0 = (bid >> 3) * 64;
    const int w = t >> 6, l = t & 63, col = l & 31, h5 = l >> 5;
    const int arow = t >> 2, kch = t & 3;
    const int aswz = (col >> 3) & 3;             // A fragment-read chunk XOR
    const int awi = arow * 32 + (kch ^ ((arow >> 3) & 3)) * 8;  // A write slot

    const float* ax = x + ((size_t)b * M + m0 + arow) * N + kch * 8;
    // per-lane panel base (kc=0, rg=w*2): offsets kc*4096 + tr*512 shorts
    const unsigned short* bpH = cpH + (((size_t)b * 256 + w * 2) * 64 + l) * 8;
    const unsigned short* bpL = cpL + (((size_t)b * 256 + w * 2) * 64 + l) * 8;

    f32x16 acc[2][2];
    acc[0][0] = (f32x16)0.f; acc[0][1] = (f32x16)0.f;
    acc[1][0] = (f32x16)0.f; acc[1][1] = (f32x16)0.f;

    float x2p = 0.f;
    float4 a0, a1;
    unsigned ph[4], pl[4];
    short8 cbh[2][2], cbl[2][2], nbh[2][2], nbl[2][2];

    auto loadB = [&](int kc0, short8 (&bh)[2][2], short8 (&bl)[2][2]) {
#pragma unroll
        for (int half = 0; half < 2; ++half)
#pragma unroll
        for (int tr = 0; tr < 2; ++tr) {
            const size_t o = (size_t)(kc0 + half) * 4096 + (size_t)tr * 512;
            bh[half][tr] = *(const short8*)(bpH + o);
            bl[half][tr] = *(const short8*)(bpL + o);
        }
    };
    auto convertA = [&](void) {   // a0,a1 -> ph/pl split bf16, exact x2 accum
        float av[8] = {a0.x, a0.y, a0.z, a0.w, a1.x, a1.y, a1.z, a1.w};
#pragma unroll
        for (int j = 0; j < 4; ++j) {
            x2p += av[2*j] * av[2*j] + av[2*j+1] * av[2*j+1];
            unsigned short h0 = bf16_rtn(av[2*j]), h1 = bf16_rtn(av[2*j+1]);
            float r0 = av[2*j]   - __uint_as_float((unsigned)h0 << 16);
            float r1 = av[2*j+1] - __uint_as_float((unsigned)h1 << 16);
            ph[j] = (unsigned)h0 | ((unsigned)h1 << 16);
            pl[j] = (unsigned)bf16_rtn(r0) | ((unsigned)bf16_rtn(r1) << 16);
        }
    };
    auto writeA = [&](void) {
        *(uint4*)&Ah[awi] = make_uint4(ph[0], ph[1], ph[2], ph[3]);
        *(uint4*)&Al[awi] = make_uint4(pl[0], pl[1], pl[2], pl[3]);
    };
    auto mfma_tile = [&](short8 (&bh)[2][2], short8 (&bl)[2][2]) {
#pragma unroll
        for (int half = 0; half < 2; ++half) {
            const int pa = (half * 2 + h5) ^ aswz;
            short8 ah[2], al2[2];
#pragma unroll
            for (int tm = 0; tm < 2; ++tm) {
                ah[tm]  = *(const short8*)&Ah[(tm*32 + col) * 32 + pa * 8];
                al2[tm] = *(const short8*)&Al[(tm*32 + col) * 32 + pa * 8];
            }
#pragma unroll
            for (int tm = 0; tm < 2; ++tm)
#pragma unroll
            for (int tr = 0; tr < 2; ++tr) {
                acc[tm][tr] = __builtin_amdgcn_mfma_f32_32x32x16_bf16(ah[tm],  bh[half][tr], acc[tm][tr], 0, 0, 0);
                acc[tm][tr] = __builtin_amdgcn_mfma_f32_32x32x16_bf16(ah[tm],  bl[half][tr], acc[tm][tr], 0, 0, 0);
                acc[tm][tr] = __builtin_amdgcn_mfma_f32_32x32x16_bf16(al2[tm], bh[half][tr], acc[tm][tr], 0, 0, 0);
            }
        }
    };
    auto xt_store = [&](int k0) {   // xT[k0+kk][m0..m0+63], coalesced 16B
        int kk = t >> 3, ms = (t & 7) * 8;
        unsigned short vv[8];
#pragma unroll
        for (int i = 0; i < 8; ++i) {
            int row = ms + i;
            vv[i] = Ah[row * 32 + (((kk >> 3) ^ ((row >> 3) & 3)) << 3) + (kk & 7)];
        }
        *(uint4*)(xT + ((size_t)b * N + k0 + kk) * M + m0 + ms) =
            make_uint4((unsigned)vv[0] | ((unsigned)vv[1] << 16),
                       (unsigned)vv[2] | ((unsigned)vv[3] << 16),
                       (unsigned)vv[4] | ((unsigned)vv[5] << 16),
                       (unsigned)vv[6] | ((unsigned)vv[7] << 16));
    };

    // ---- prologue: A(0) -> LDS, B(0)+B(32) -> regs, x(32) -> regs ----
    a0 = *(const float4*)(ax);
    a1 = *(const float4*)(ax + 4);
    loadB(0, cbh, cbl);
    convertA();
    writeA();
    a0 = *(const float4*)(ax + 32);
    a1 = *(const float4*)(ax + 36);
    loadB(2, nbh, nbl);
    asm volatile("s_waitcnt lgkmcnt(0)" ::: "memory");
    __builtin_amdgcn_sched_barrier(0);
    __builtin_amdgcn_s_barrier();
    __builtin_amdgcn_sched_barrier(0);

    // ---- step: compute kk (A in LDS, B in cur regs); refill cur with B(kk+64);
    //      stage A(kk+32); prefetch x(kk+64). lgkm-only barriers. ----
    auto step = [&](int kk, short8 (&ch)[2][2], short8 (&cl)[2][2]) {
        xt_store(kk);
        mfma_tile(ch, cl);
        if (kk + 64 < N) loadB((kk + 64) >> 4, ch, cl);   // WAR: after consumption
        if (kk + 32 < N) {
            convertA();                                   // tile kk+32
            __builtin_amdgcn_sched_barrier(0);
            __builtin_amdgcn_s_barrier();                 // readers of A(kk) done
            __builtin_amdgcn_sched_barrier(0);
            writeA();                                     // A(kk+32)
            if (kk + 64 < N) {
                a0 = *(const float4*)(ax + kk + 64);
                a1 = *(const float4*)(ax + kk + 68);
            }
            asm volatile("s_waitcnt lgkmcnt(0)" ::: "memory");
            __builtin_amdgcn_sched_barrier(0);
            __builtin_amdgcn_s_barrier();                 // A(kk+32) visible
            __builtin_amdgcn_sched_barrier(0);
        }
    };

#pragma unroll 1
    for (int k0 = 0; k0 < N; k0 += 64) {
        step(k0, cbh, cbl);
        step(k0 + 32, nbh, nbl);
    }

    // ---- epilogue (scratch aliases now-dead LDS) ----
    __syncthreads();                                  // all loop LDS reads done
    float* x2s = (float*)&Ah[0];                      // 256 B
    float (*redm)[64] = (float (*)[64])&Al[0];        // 1 KB
    float (*reds)[64] = (float (*)[64])((float*)&Al[0] + 256);  // next 1 KB

    x2p += __shfl_xor(x2p, 1);
    x2p += __shfl_xor(x2p, 2);
    if (kch == 0) x2s[arow] = x2p;
    __syncthreads();

    const float ia = 1.4426950408889634f / alpha_p[0];  // log2(e)/alpha
    float v2c[2];
#pragma unroll
    for (int tr = 0; tr < 2; ++tr)
        v2c[tr] = v2g[b * R + w * 64 + tr * 32 + col];

    // d = relu(x2 - 2xv + v2); wave-local row min; stage to LDS
#pragma unroll
    for (int tm = 0; tm < 2; ++tm)
#pragma unroll
    for (int reg = 0; reg < 16; ++reg) {
        int rowl = (reg & 3) + 8 * (reg >> 2) + 4 * h5;
        float x2v = x2s[tm * 32 + rowl];
        float mn;
#pragma unroll
        for (int tr = 0; tr < 2; ++tr) {
            float d = x2v - 2.f * acc[tm][tr][reg] + v2c[tr];
            d = fmaxf(d, 0.f);
            acc[tm][tr][reg] = d;
            mn = (tr == 0) ? d : fminf(mn, d);
        }
        mn = fminf(mn, __shfl_xor(mn, 1));
        mn = fminf(mn, __shfl_xor(mn, 2));
        mn = fminf(mn, __shfl_xor(mn, 4));
        mn = fminf(mn, __shfl_xor(mn, 8));
        mn = fminf(mn, __shfl_xor(mn, 16));
        if (col == 0) redm[w][tm * 32 + rowl] = mn;
    }
    __syncthreads();

    // exp + row sum
#pragma unroll
    for (int tm = 0; tm < 2; ++tm)
#pragma unroll
    for (int reg = 0; reg < 16; ++reg) {
        int m = tm * 32 + (reg & 3) + 8 * (reg >> 2) + 4 * h5;
        float mn = fminf(fminf(redm[0][m], redm[1][m]), fminf(redm[2][m], redm[3][m]));
        float s = 0.f;
#pragma unroll
        for (int tr = 0; tr < 2; ++tr) {
            float e = exp2f((mn - acc[tm][tr][reg]) * ia);
            acc[tm][tr][reg] = e;
            s += e;
        }
        s += __shfl_xor(s, 1); s += __shfl_xor(s, 2); s += __shfl_xor(s, 4);
        s += __shfl_xor(s, 8); s += __shfl_xor(s, 16);
        if (col == 0) reds[w][m] = s;
    }
    __syncthreads();

    // normalize, write u (fp32), accumulate colsum, pack uT (bf16)
    float* ub = u_out + ((size_t)b * M + m0) * R + w * 64;
    float cs[2] = {0.f, 0.f};
#pragma unroll
    for (int tm = 0; tm < 2; ++tm)
#pragma unroll
    for (int reg = 0; reg < 16; ++reg) {
        int rowl = (reg & 3) + 8 * (reg >> 2) + 4 * h5;
        int m = tm * 32 + rowl;
        float inv = 1.f / (reds[0][m] + reds[1][m] + reds[2][m] + reds[3][m]);
#pragma unroll
        for (int tr = 0; tr < 2; ++tr) {
            float uu = acc[tm][tr][reg] * inv;
            acc[tm][tr][reg] = uu;
            ub[(size_t)m * R + tr * 32 + col] = uu;
            cs[tr] += uu;
        }
    }
    unsigned short* uTb = uT + ((size_t)b * R + w * 64) * M + m0;
#pragma unroll
    for (int tm = 0; tm < 2; ++tm)
#pragma unroll
    for (int tr = 0; tr < 2; ++tr)
#pragma unroll
    for (int rq = 0; rq < 4; ++rq) {
        uint2 p;
        p.x = (unsigned)bf16_rtn(acc[tm][tr][rq*4+0]) | ((unsigned)bf16_rtn(acc[tm][tr][rq*4+1]) << 16);
        p.y = (unsigned)bf16_rtn(acc[tm][tr][rq*4+2]) | ((unsigned)bf16_rtn(acc[tm][tr][rq*4+3]) << 16);
        *(uint2*)(uTb + (size_t)(tr*32 + col) * M + tm*32 + 8*rq + 4*h5) = p;
    }
    cs[0] += __shfl_xor(cs[0], 32);
    cs[1] += __shfl_xor(cs[1], 32);
    if (h5 == 0) {
        atomicAdd(&colsum[b * R + w * 64 + col], cs[0]);
        atomicAdd(&colsum[b * R + w * 64 + 32 + col], cs[1]);
    }
}

// ---------------------------------------------------------------------------
// K2: part[slab][b][n][r] = sum_{m in slab} xT[n][m]*uT[r][m].
// R0 version (proven; restructuring measured neutral in R1/R2).
// ---------------------------------------------------------------------------
__global__ __launch_bounds__(256, 2) void ekm_k2(
    const unsigned short* __restrict__ xT, const unsigned short* __restrict__ uT,
    float* __restrict__ part)
{
    __shared__ unsigned short XA[128 * 32], UB[128 * 32];
    const int t = threadIdx.x;
    const int nt = blockIdx.x >> 1, rt = blockIdx.x & 1;
    const int slab = blockIdx.y, b = blockIdx.z;
    const int n0 = nt * 128, r0 = rt * 128;
    const int w = t >> 6, l = t & 63, col = l & 31, h5 = l >> 5;
    const int wn = w >> 1, wr = w & 1;
    const int cswz = (t & 3) ^ ((t >> 3) & 3);
    const int pswz = (col >> 1) & 3;

    const unsigned short* xs = xT + ((size_t)b * N + n0 + (t >> 2)) * M + slab * 1024 + cswz * 8;
    const unsigned short* us = uT + ((size_t)b * R + r0 + (t >> 2)) * M + slab * 1024 + cswz * 8;

    f32x16 acc[2][2];
    acc[0][0] = (f32x16)0.f; acc[0][1] = (f32x16)0.f;
    acc[1][0] = (f32x16)0.f; acc[1][1] = (f32x16)0.f;

    for (int k0 = 0; k0 < 1024; k0 += 32) {
        __syncthreads();
#pragma unroll
        for (int i = 0; i < 2; ++i) {
            gll16(xs + k0 + (size_t)i * 64 * M, XA + i * 2048 + t * 8);
            gll16(us + k0 + (size_t)i * 64 * M, UB + i * 2048 + t * 8);
        }
        __syncthreads();
#pragma unroll
        for (int half = 0; half < 2; ++half) {
            const int pc = (half * 2 + h5) ^ pswz;
            short8 af[2], bf2[2];
#pragma unroll
            for (int tm = 0; tm < 2; ++tm)
                af[tm] = *(const short8*)&XA[(wn*64 + tm*32 + col) * 32 + pc*8];
#pragma unroll
            for (int tr = 0; tr < 2; ++tr)
                bf2[tr] = *(const short8*)&UB[(wr*64 + tr*32 + col) * 32 + pc*8];
#pragma unroll
            for (int tm = 0; tm < 2; ++tm)
#pragma unroll
            for (int tr = 0; tr < 2; ++tr)
                acc[tm][tr] = __builtin_amdgcn_mfma_f32_32x32x16_bf16(af[tm], bf2[tr], acc[tm][tr], 0, 0, 0);
        }
    }

    float* pb = part + (size_t)slab * ((size_t)B * N * R) + (size_t)b * N * R;
#pragma unroll
    for (int tm = 0; tm < 2; ++tm)
#pragma unroll
    for (int reg = 0; reg < 16; ++reg) {
        int n = n0 + wn*64 + tm*32 + (reg & 3) + 8*(reg >> 2) + 4*h5;
#pragma unroll
        for (int tr = 0; tr < 2; ++tr)
            pb[(size_t)n * R + r0 + wr*64 + tr*32 + col] = acc[tm][tr][reg];
    }
}

// ---------------------------------------------------------------------------
// Kred: v = (sum of 8 partial slabs) / (colsum + eps), float4 per thread.
// ---------------------------------------------------------------------------
__global__ __launch_bounds__(256) void ekm_red(
    const float* __restrict__ part, const float* __restrict__ colsum,
    float* __restrict__ v_out)
{
    size_t o = ((size_t)blockIdx.x * 256 + threadIdx.x) * 4;
    float sx = 0.f, sy = 0.f, sz = 0.f, sw = 0.f;
#pragma unroll
    for (int sl = 0; sl < 8; ++sl) {
        float4 p = *(const float4*)(part + (size_t)sl * B * N * R + o);
        sx += p.x; sy += p.y; sz += p.z; sw += p.w;
    }
    int b = (int)(o >> 17);           // N*R = 131072
    int r = (int)(o & (R - 1));
    float4 cs = *(const float4*)(colsum + b * R + r);
    float4 vo;
    vo.x = sx / (cs.x + EPSF);
    vo.y = sy / (cs.y + EPSF);
    vo.z = sz / (cs.z + EPSF);
    vo.w = sw / (cs.w + EPSF);
    *(float4*)(v_out + o) = vo;
}

extern "C" void kernel_launch(void* const* d_in, const int* in_sizes, int n_in,
                              void* d_out, int out_size, void* d_ws, size_t ws_size,
                              hipStream_t stream) {
    const float* x     = (const float*)d_in[0];
    const float* alpha = (const float*)d_in[1];
    const int*   inds  = (const int*)d_in[2];

    float* u_out = (float*)d_out;                    // B*M*R fp32
    float* v_out = u_out + (size_t)B * M * R;        // B*N*R fp32

    char* ws = (char*)d_ws;
    const size_t CH = (size_t)B * R * 512 * 2;       // 2 MB   cpH / cpL
    unsigned short* cpH    = (unsigned short*)ws;
    unsigned short* cpL    = (unsigned short*)(ws + CH);
    float*          v2g    = (float*)(ws + 2 * CH);
    float*          colsum = (float*)(ws + 2 * CH + (size_t)B * R * 4);
    char* p = ws + 2 * CH + 2 * (size_t)B * R * 4;
    unsigned short* xT = (unsigned short*)p;          p += (size_t)B * N * M * 2;  // 67 MB
    unsigned short* uT = (unsigned short*)p;          p += (size_t)B * R * M * 2;  // 33.5 MB
    float*          part = (float*)p;                 // 8 * B*N*R * 4 = 33.5 MB

    hipMemsetAsync(colsum, 0, (size_t)B * R * sizeof(float), stream);

    ekm_kc<<<dim3(16, B), 256, 0, stream>>>(x, inds, cpH, cpL, v2g);
    ekm_k1<<<dim3(M / 64 * B), 256, 0, stream>>>(x, alpha, cpH, cpL, v2g,
                                                 u_out, uT, xT, colsum);
    ekm_k2<<<dim3(8, 8, B), 256, 0, stream>>>(xT, uT, part);
    ekm_red<<<(B * N * R / 4) / 256, 256, 0, stream>>>(part, colsum, v_out);
}